// Round 1
// baseline (432.856 us; speedup 1.0000x reference)
//
#include <hip/hip_runtime.h>
#include <math.h>

#define NW 4
#define KLEN 16
#define LEVELS 6
#define PI_D 3.14159265358979323846

// Output row length per (b, n)
#define T_OUT 131166LL

// ---------------------------------------------------------------------------
// Filter constraint kernel: computes the 8 constrained filters (4 lp + 4 hp)
// filt[j] = sum_k h[k] * g(j-k),  g(d) = (1/64)[w0 + 2*sum_{m=1}^{31} w_m cos(pi m d/32) + w32 cos(pi d)]
// then L2-normalize * sqrt(2). One block, 256 threads, double precision.
// ---------------------------------------------------------------------------
__global__ void constrain_filters_kernel(const float* __restrict__ lo,
                                         const float* __restrict__ hi,
                                         float* __restrict__ out /* [8][16] */) {
    __shared__ double g[8][31];
    __shared__ float filt[8][16];
    int tid = threadIdx.x;

    // Phase 1: 8 filters x 31 displacement values
    if (tid < 8 * 31) {
        int f  = tid / 31;
        int di = tid % 31;
        int d  = di - 15;
        double center = ((double)(f & 3) + 0.5) / 4.0;
        double target = (f < 4) ? center * 0.5 : center * 0.5 + 0.5;
        double acc = 0.0;
        for (int m = 0; m <= 32; ++m) {
            double fr = (double)m / 32.0;
            double z  = (fr - target) * 4.0;           // width = 1/4
            double w  = exp(-z * z);
            double c  = cos(PI_D * (double)m * (double)d / 32.0);
            double coef = (m == 0 || m == 32) ? 1.0 : 2.0;
            acc += coef * w * c;
        }
        g[f][di] = acc / 64.0;
    }
    __syncthreads();

    // Phase 2: filt[f][j] = sum_k h[k] g[f][j-k+15]
    if (tid < 128) {
        int f = tid >> 4, j = tid & 15;
        const float* h = (f < 4) ? (lo + f * KLEN) : (hi + (f - 4) * KLEN);
        double acc = 0.0;
        for (int k = 0; k < KLEN; ++k) {
            acc += (double)h[k] * g[f][j - k + 15];
        }
        filt[f][j] = (float)acc;
    }
    __syncthreads();

    // Phase 3: normalize * sqrt(2)
    if (tid < 128) {
        int f = tid >> 4, j = tid & 15;
        double s = 0.0;
        for (int k = 0; k < KLEN; ++k) { double v = filt[f][k]; s += v * v; }
        double nrm = sqrt(s);
        if (nrm < 1e-12) nrm = 1e-12;
        out[f * KLEN + j] = (float)((double)filt[f][j] / nrm * 1.4142135623730951);
    }
}

// ---------------------------------------------------------------------------
// One DWT level: fused approx+detail stride-2 cross-correlation, zero pad 15.
// out[t] = sum_{k=0}^{15} x[2t + k - 15] * filt[k]
// grid: (ceil(Lout/256), NW, BATCH), block 256.
// ---------------------------------------------------------------------------
__global__ void dwt_level_kernel(const float* __restrict__ x,
                                 int Lin, int Lout,
                                 long long xStrideB, long long xStrideN,
                                 const float* __restrict__ filters, /* [8][16] */
                                 float* __restrict__ aOut,
                                 long long aStrideB, long long aStrideN,
                                 float* __restrict__ dOut,
                                 long long dStrideB, long long dStrideN) {
    int n = blockIdx.y;
    int b = blockIdx.z;
    int t = blockIdx.x * blockDim.x + threadIdx.x;
    if (t >= Lout) return;

    const float* xr = x + (long long)b * xStrideB + (long long)n * xStrideN;
    const float* lp = filters + n * KLEN;
    const float* hp = filters + (NW + n) * KLEN;

    int base = 2 * t - 15;
    float a = 0.f, dv = 0.f;
#pragma unroll
    for (int k = 0; k < KLEN; ++k) {
        int idx = base + k;
        float v = (idx >= 0 && idx < Lin) ? xr[idx] : 0.f;
        a  += v * lp[k];
        dv += v * hp[k];
    }
    aOut[(long long)b * aStrideB + (long long)n * aStrideN + t] = a;
    dOut[(long long)b * dStrideB + (long long)n * dStrideN + t] = dv;
}

// ---------------------------------------------------------------------------
extern "C" void kernel_launch(void* const* d_in, const int* in_sizes, int n_in,
                              void* d_out, int out_size, void* d_ws, size_t ws_size,
                              hipStream_t stream) {
    const float* signal = (const float*)d_in[0];
    const float* lo     = (const float*)d_in[1];
    const float* hi     = (const float*)d_in[2];
    float* out = (float*)d_out;
    float* ws  = (float*)d_ws;

    // ws layout: [0..255] filters (128 used), then bufA, then bufB
    float* filters = ws;
    float* bufA = ws + 256;
    float* bufB = bufA + 256LL * 65544;   // bufA sized for L1 (and L3, L5)

    constrain_filters_kernel<<<1, 256, 0, stream>>>(lo, hi, filters);

    // Level lengths
    const int L[LEVELS + 1] = {131072, 65544, 32780, 16398, 8207, 4111, 2063};
    // Detail output offsets within each (b,n) row of length T_OUT:
    // [approx6 | d6 | d5 | d4 | d3 | d2 | d1]
    const long long det_off[LEVELS + 1] = {0, 65622, 32842, 16444, 8237, 4126, 2063};

    const float* in = signal;
    long long sB = 131072, sN = 0;   // level-1 input: broadcast over n
    float* bufs[2] = {bufA, bufB};

    for (int lev = 1; lev <= LEVELS; ++lev) {
        int Lin = L[lev - 1], Lout = L[lev];
        float* aout; long long aB, aN;
        if (lev < LEVELS) {
            aout = bufs[(lev - 1) & 1];
            aN = Lout; aB = 4LL * Lout;
        } else {
            aout = out;                 // final approx goes to offset 0
            aN = T_OUT; aB = 4LL * T_OUT;
        }
        dim3 grid((Lout + 255) / 256, NW, 64);
        dwt_level_kernel<<<grid, 256, 0, stream>>>(
            in, Lin, Lout, sB, sN, filters,
            aout, aB, aN,
            out + det_off[lev], 4LL * T_OUT, T_OUT);
        if (lev < LEVELS) {
            in = aout; sB = aB; sN = aN;
        }
    }
}

// Round 2
// 262.938 us; speedup vs baseline: 1.6462x; 1.6462x over previous
//
#include <hip/hip_runtime.h>
#include <math.h>

#define NW 4
#define KLEN 16
#define LEVELS 6
#define PI_D 3.14159265358979323846

// Output row length per (b, n)
#define T_OUT 131166LL

// ---------------------------------------------------------------------------
// Filter constraint kernel (unchanged from round 1 — verified correct).
// ---------------------------------------------------------------------------
__global__ void constrain_filters_kernel(const float* __restrict__ lo,
                                         const float* __restrict__ hi,
                                         float* __restrict__ out /* [8][16] */) {
    __shared__ double g[8][31];
    __shared__ float filt[8][16];
    int tid = threadIdx.x;

    if (tid < 8 * 31) {
        int f  = tid / 31;
        int di = tid % 31;
        int d  = di - 15;
        double center = ((double)(f & 3) + 0.5) / 4.0;
        double target = (f < 4) ? center * 0.5 : center * 0.5 + 0.5;
        double acc = 0.0;
        for (int m = 0; m <= 32; ++m) {
            double fr = (double)m / 32.0;
            double z  = (fr - target) * 4.0;           // width = 1/4
            double w  = exp(-z * z);
            double c  = cos(PI_D * (double)m * (double)d / 32.0);
            double coef = (m == 0 || m == 32) ? 1.0 : 2.0;
            acc += coef * w * c;
        }
        g[f][di] = acc / 64.0;
    }
    __syncthreads();

    if (tid < 128) {
        int f = tid >> 4, j = tid & 15;
        const float* h = (f < 4) ? (lo + f * KLEN) : (hi + (f - 4) * KLEN);
        double acc = 0.0;
        for (int k = 0; k < KLEN; ++k) {
            acc += (double)h[k] * g[f][j - k + 15];
        }
        filt[f][j] = (float)acc;
    }
    __syncthreads();

    if (tid < 128) {
        int f = tid >> 4, j = tid & 15;
        double s = 0.0;
        for (int k = 0; k < KLEN; ++k) { double v = filt[f][k]; s += v * v; }
        double nrm = sqrt(s);
        if (nrm < 1e-12) nrm = 1e-12;
        out[f * KLEN + j] = (float)((double)filt[f][j] / nrm * 1.4142135623730951);
    }
}

// ---------------------------------------------------------------------------
// Vectorized 8-element store with runtime alignment dispatch (block-uniform
// branch: base alignment is fixed per (b,n) row, t0 is always %8).
// ---------------------------------------------------------------------------
__device__ __forceinline__ void store8(float* __restrict__ p, const float* v) {
    uintptr_t a = (uintptr_t)p;
    if ((a & 15) == 0) {
        ((float4*)p)[0] = make_float4(v[0], v[1], v[2], v[3]);
        ((float4*)p)[1] = make_float4(v[4], v[5], v[6], v[7]);
    } else if ((a & 7) == 0) {
        ((float2*)p)[0] = make_float2(v[0], v[1]);
        ((float2*)p)[1] = make_float2(v[2], v[3]);
        ((float2*)p)[2] = make_float2(v[4], v[5]);
        ((float2*)p)[3] = make_float2(v[6], v[7]);
    } else {
#pragma unroll
        for (int j = 0; j < 8; ++j) p[j] = v[j];
    }
}

// ---------------------------------------------------------------------------
// One DWT level, 8 outputs per thread with register-window reuse.
// out[t] = sum_{k=0}^{15} x[2t + k - 15] * filt[k]   (zero pad outside [0,Lin))
// Thread g handles t in [8g, 8g+8); input window = x[16g-15 .. 16g+14],
// loaded as 8 aligned float4 covering x[16g-16 .. 16g+15].
// grid: (ceil(Lout/2048), NW, BATCH), block 256.
// ---------------------------------------------------------------------------
__global__ __launch_bounds__(256) void dwt_level_v2(
        const float* __restrict__ x, int Lin, int Lout,
        long long xStrideB, long long xStrideN,
        const float* __restrict__ filters, /* [8][16] */
        float* __restrict__ aOut, long long aStrideB, long long aStrideN,
        float* __restrict__ dOut, long long dStrideB, long long dStrideN) {
    int n = blockIdx.y;
    int b = blockIdx.z;
    int g = blockIdx.x * blockDim.x + threadIdx.x;
    int t0 = g << 3;
    if (t0 >= Lout) return;

    const float* __restrict__ xr = x + (long long)b * xStrideB + (long long)n * xStrideN;

    // Filters: block-uniform index -> scalar loads -> SGPRs.
    float lp[KLEN], hp[KLEN];
#pragma unroll
    for (int k = 0; k < KLEN; ++k) {
        lp[k] = filters[n * KLEN + k];
        hp[k] = filters[(NW + n) * KLEN + k];
    }

    int s = (t0 << 1) - 16;
    float xs[32];
    bool fast = (s >= 0) && (s + 32 <= Lin) && (t0 + 8 <= Lout);
    if (fast) {
        const float4* __restrict__ p = (const float4*)(xr + s);
#pragma unroll
        for (int i = 0; i < 8; ++i) {
            float4 v = p[i];
            xs[4 * i + 0] = v.x; xs[4 * i + 1] = v.y;
            xs[4 * i + 2] = v.z; xs[4 * i + 3] = v.w;
        }
    } else {
#pragma unroll
        for (int i = 0; i < 32; ++i) {
            int idx = s + i;
            xs[i] = (idx >= 0 && idx < Lin) ? xr[idx] : 0.f;
        }
    }

    float av[8], dv[8];
#pragma unroll
    for (int j = 0; j < 8; ++j) {
        float a = 0.f, d = 0.f;
#pragma unroll
        for (int k = 0; k < KLEN; ++k) {
            float v = xs[2 * j + 1 + k];   // x[2(t0+j)-15+k] lives at xs[2j+1+k]
            a = fmaf(v, lp[k], a);
            d = fmaf(v, hp[k], d);
        }
        av[j] = a; dv[j] = d;
    }

    float* ap = aOut + (long long)b * aStrideB + (long long)n * aStrideN + t0;
    float* dp = dOut + (long long)b * dStrideB + (long long)n * dStrideN + t0;
    if (t0 + 8 <= Lout) {
        store8(ap, av);
        store8(dp, dv);
    } else {
#pragma unroll
        for (int j = 0; j < 8; ++j) {
            if (t0 + j < Lout) { ap[j] = av[j]; dp[j] = dv[j]; }
        }
    }
}

// ---------------------------------------------------------------------------
extern "C" void kernel_launch(void* const* d_in, const int* in_sizes, int n_in,
                              void* d_out, int out_size, void* d_ws, size_t ws_size,
                              hipStream_t stream) {
    const float* signal = (const float*)d_in[0];
    const float* lo     = (const float*)d_in[1];
    const float* hi     = (const float*)d_in[2];
    float* out = (float*)d_out;
    float* ws  = (float*)d_ws;

    // ws layout: [0..255] filters, then bufA (levels 1,3,5), bufB (levels 2,4)
    float* filters = ws;
    float* bufA = ws + 256;
    float* bufB = bufA + 256LL * 65544;

    constrain_filters_kernel<<<1, 256, 0, stream>>>(lo, hi, filters);

    const int L[LEVELS + 1] = {131072, 65544, 32780, 16398, 8207, 4111, 2063};
    // Packed output: [approx6 | d6 | d5 | d4 | d3 | d2 | d1]
    const long long det_off[LEVELS + 1] = {0, 65622, 32842, 16444, 8237, 4126, 2063};

    const float* in = signal;
    long long sB = 131072, sN = 0;   // level-1 input: broadcast over n
    float* bufs[2] = {bufA, bufB};

    for (int lev = 1; lev <= LEVELS; ++lev) {
        int Lin = L[lev - 1], Lout = L[lev];
        float* aout; long long aB, aN;
        if (lev < LEVELS) {
            aout = bufs[(lev - 1) & 1];
            aN = (long long)((Lout + 3) & ~3);   // pad stride to %4 for float4 I/O
            aB = 4LL * aN;
        } else {
            aout = out;                 // final approx goes to offset 0
            aN = T_OUT; aB = 4LL * T_OUT;
        }
        dim3 grid((Lout + 2047) / 2048, NW, 64);
        dwt_level_v2<<<grid, 256, 0, stream>>>(
            in, Lin, Lout, sB, sN, filters,
            aout, aB, aN,
            out + det_off[lev], 4LL * T_OUT, T_OUT);
        if (lev < LEVELS) {
            in = aout; sB = aB; sN = aN;
        }
    }
}

// Round 6
// 237.947 us; speedup vs baseline: 1.8191x; 1.1050x over previous
//
#include <hip/hip_runtime.h>
#include <math.h>

#define NW 4
#define KLEN 16
#define LEVELS 6
#define PI_D 3.14159265358979323846
#define T_OUT 131166LL
#define SIG_LEN 131072

// Fused-cascade chunk geometry: block owns 2048 level-1 outputs (4096 input samples).
// Halos H_l satisfy H_{l-1} = 2*H_l + 16 so every level's pair-p window starts at
// src[4p] (float4-aligned LDS reads, conflict-free 16B lane stride).
// H: L1=496 L2=240 L3=112 L4=48 L5=16 L6=0
// NA_l = C_l + H_l: 2544, 1264, 624, 304, 144, 64   (C_l = 2048>>(l-1))
// NX (input chunk) = 1008 + 4096 = 5104 floats
#define NCHUNK 33

// ---------------------------------------------------------------------------
// Filter constraint kernel (verified correct, unchanged).
// ---------------------------------------------------------------------------
__global__ void constrain_filters_kernel(const float* __restrict__ lo,
                                         const float* __restrict__ hi,
                                         float* __restrict__ out /* [8][16] */) {
    __shared__ double g[8][31];
    __shared__ float filt[8][16];
    int tid = threadIdx.x;

    if (tid < 8 * 31) {
        int f  = tid / 31;
        int di = tid % 31;
        int d  = di - 15;
        double center = ((double)(f & 3) + 0.5) / 4.0;
        double target = (f < 4) ? center * 0.5 : center * 0.5 + 0.5;
        double acc = 0.0;
        for (int m = 0; m <= 32; ++m) {
            double fr = (double)m / 32.0;
            double z  = (fr - target) * 4.0;           // width = 1/4
            double w  = exp(-z * z);
            double c  = cos(PI_D * (double)m * (double)d / 32.0);
            double coef = (m == 0 || m == 32) ? 1.0 : 2.0;
            acc += coef * w * c;
        }
        g[f][di] = acc / 64.0;
    }
    __syncthreads();

    if (tid < 128) {
        int f = tid >> 4, j = tid & 15;
        const float* h = (f < 4) ? (lo + f * KLEN) : (hi + (f - 4) * KLEN);
        double acc = 0.0;
        for (int k = 0; k < KLEN; ++k) {
            acc += (double)h[k] * g[f][j - k + 15];
        }
        filt[f][j] = (float)acc;
    }
    __syncthreads();

    if (tid < 128) {
        int f = tid >> 4, j = tid & 15;
        double s = 0.0;
        for (int k = 0; k < KLEN; ++k) { double v = filt[f][k]; s += v * v; }
        double nrm = sqrt(s);
        if (nrm < 1e-12) nrm = 1e-12;
        out[f * KLEN + j] = (float)((double)filt[f][j] / nrm * 1.4142135623730951);
    }
}

// ---------------------------------------------------------------------------
__device__ __forceinline__ float rf(float v) {
    return __int_as_float(__builtin_amdgcn_readfirstlane(__float_as_int(v)));
}

// One level inside the fused cascade. Pair p computes outputs t0 = tBase+2p,
// t0+1 from src[4p .. 4p+19] (LDS, float4-aligned):
//   out[t] = sum_k src_global[2t-15+k]*f[k];  x[2t0-15] sits at src[4p+1].
__device__ __forceinline__ void level_step(
        const float* __restrict__ src, float* __restrict__ dst,
        int P, int tBase, int Ll, int Mlo, int Mhi,
        float* __restrict__ det, float* __restrict__ apx,
        const float* __restrict__ lp, const float* __restrict__ hp,
        int tid, int nthr) {
    for (int p = tid; p < P; p += nthr) {
        const float* w = src + 4 * p;
        float4 w0 = *(const float4*)(w);
        float4 w1 = *(const float4*)(w + 4);
        float4 w2 = *(const float4*)(w + 8);
        float4 w3 = *(const float4*)(w + 12);
        float4 w4 = *(const float4*)(w + 16);
        float wv[20] = {w0.x, w0.y, w0.z, w0.w, w1.x, w1.y, w1.z, w1.w,
                        w2.x, w2.y, w2.z, w2.w, w3.x, w3.y, w3.z, w3.w,
                        w4.x, w4.y, w4.z, w4.w};
        float a0 = 0.f, d0 = 0.f, a1 = 0.f, d1 = 0.f;
#pragma unroll
        for (int k = 0; k < KLEN; ++k) {
            float v0 = wv[1 + k];
            float v1 = wv[3 + k];
            a0 = fmaf(v0, lp[k], a0);
            d0 = fmaf(v0, hp[k], d0);
            a1 = fmaf(v1, lp[k], a1);
            d1 = fmaf(v1, hp[k], d1);
        }
        int t0 = tBase + 2 * p;
        int t1 = t0 + 1;
        if (dst) {
            float2 st;
            st.x = (t0 < Ll) ? a0 : 0.f;   // zero past-end so next level reads pad
            st.y = (t1 < Ll) ? a1 : 0.f;
            *(float2*)(dst + 2 * p) = st;
        }
        if (t0 >= Mlo && t0 < Mhi) det[t0] = d0;
        if (t1 >= Mlo && t1 < Mhi) det[t1] = d1;
        if (apx) {
            if (t0 >= Mlo && t0 < Mhi) apx[t0] = a0;
            if (t1 >= Mlo && t1 < Mhi) apx[t1] = a1;
        }
    }
}

// ---------------------------------------------------------------------------
// Whole 6-level cascade for one (chunk, wavelet, batch) in one block.
// grid (NCHUNK, NW, BATCH), block 512. LDS = 39936 B -> 4 blocks/CU.
// ---------------------------------------------------------------------------
__global__ __launch_bounds__(512) void dwt_fused(
        const float* __restrict__ x, const float* __restrict__ filters,
        float* __restrict__ out) {
    __shared__ float lds[9984];
    float* xs = lds;            // 5104
    float* s1 = lds + 5104;     // 2544
    float* s2 = s1 + 2544;      // 1264
    float* s3 = s2 + 1264;      // 624
    float* s4 = s3 + 624;       // 304
    float* s5 = s4 + 304;       // 144

    const int c   = blockIdx.x;
    const int n   = blockIdx.y;
    const int b   = blockIdx.z;
    const int tid = threadIdx.x;

    // Filters -> SGPRs (block-uniform).
    float lp[KLEN], hp[KLEN];
#pragma unroll
    for (int k = 0; k < KLEN; ++k) {
        lp[k] = rf(filters[n * KLEN + k]);
        hp[k] = rf(filters[(NW + n) * KLEN + k]);
    }

    // Stage input chunk [4096c-1008, 4096c+4096) with zero padding.
    const float* __restrict__ xrow = x + (long long)b * SIG_LEN;
    const int Xlo = 4096 * c - 1008;
    for (int i = tid; i < 1276; i += 512) {
        int g = Xlo + 4 * i;
        float4 v;
        if (g >= 0 && g + 4 <= SIG_LEN) {
            v = *(const float4*)(xrow + g);
        } else {
            v.x = (g + 0 >= 0 && g + 0 < SIG_LEN) ? xrow[g + 0] : 0.f;
            v.y = (g + 1 >= 0 && g + 1 < SIG_LEN) ? xrow[g + 1] : 0.f;
            v.z = (g + 2 >= 0 && g + 2 < SIG_LEN) ? xrow[g + 2] : 0.f;
            v.w = (g + 3 >= 0 && g + 3 < SIG_LEN) ? xrow[g + 3] : 0.f;
        }
        *(float4*)(xs + 4 * i) = v;
    }
    __syncthreads();

    float* __restrict__ row = out + ((long long)b * NW + n) * T_OUT;

    // Level tables: L_l, C_l, H_l, det_off
    // L: 65544 32780 16398 8207 4111 2063
    {   // level 1
        int M = 2048 * c, Mhi = min(M + 2048, 65544);
        level_step(xs, s1, 1272, M - 496, 65544, M, Mhi, row + 65622, nullptr,
                   lp, hp, tid, 512);
    }
    __syncthreads();
    {   // level 2
        int M = 1024 * c, Mhi = min(M + 1024, 32780);
        level_step(s1, s2, 632, M - 240, 32780, M, Mhi, row + 32842, nullptr,
                   lp, hp, tid, 512);
    }
    __syncthreads();
    {   // level 3
        int M = 512 * c, Mhi = min(M + 512, 16398);
        level_step(s2, s3, 312, M - 112, 16398, M, Mhi, row + 16444, nullptr,
                   lp, hp, tid, 512);
    }
    __syncthreads();
    {   // level 4
        int M = 256 * c, Mhi = min(M + 256, 8207);
        level_step(s3, s4, 152, M - 48, 8207, M, Mhi, row + 8237, nullptr,
                   lp, hp, tid, 512);
    }
    __syncthreads();
    {   // level 5
        int M = 128 * c, Mhi = min(M + 128, 4111);
        level_step(s4, s5, 72, M - 16, 4111, M, Mhi, row + 4126, nullptr,
                   lp, hp, tid, 512);
    }
    __syncthreads();
    {   // level 6: details at row+2063, final approx at row+0
        int M = 64 * c, Mhi = min(M + 64, 2063);
        level_step(s5, nullptr, 32, M, 2063, M, Mhi, row + 2063, row,
                   lp, hp, tid, 512);
    }
}

// ---------------------------------------------------------------------------
extern "C" void kernel_launch(void* const* d_in, const int* in_sizes, int n_in,
                              void* d_out, int out_size, void* d_ws, size_t ws_size,
                              hipStream_t stream) {
    const float* signal = (const float*)d_in[0];
    const float* lo     = (const float*)d_in[1];
    const float* hi     = (const float*)d_in[2];
    float* out = (float*)d_out;
    float* ws  = (float*)d_ws;

    float* filters = ws;   // [8][16]

    constrain_filters_kernel<<<1, 256, 0, stream>>>(lo, hi, filters);

    dim3 grid(NCHUNK, NW, 64);
    dwt_fused<<<grid, 512, 0, stream>>>(signal, filters, out);
}